// Round 1
// baseline (1531.146 us; speedup 1.0000x reference)
//
#include <hip/hip_runtime.h>
#include <math.h>

#define NPTS 2048
#define NB 8
#define R 2        // rows per thread
#define NW 16      // waves per block = column chunks
#define BROWS 128  // rows per block
#define CPAIR 64   // col-pairs per wave chunk (128 cols)

// colpack layout per (mat,b): 2048 cols -> 1024 pairs -> 256 groups of 4 pairs.
// group g (32 floats = 128B): [A0 A1 A2 A3 | B0 B1 B2 B3], A=(x0,x1,y0,y1),
// B=(z0,z1,w0,w1) with w = (h - 0.5|q|^2) * c_of_consuming_sweep.
// Static parts written by emd_init (both ping-pong buffers); w-parts written by
// the previous sweep's merge phase with c_next. Ping-pong avoids the
// same-dispatch read/write race (readers of mat' run concurrently with the
// merge that repacks mat').
#define CPK_FLOATS 8192  // per (mat,b): 256 groups * 32 floats

typedef float v2f __attribute__((ext_vector_type(2)));
typedef float v8f __attribute__((ext_vector_type(8)));

__device__ __forceinline__ float wexp2(float v) { return __builtin_amdgcn_exp2f(v); }
__device__ __forceinline__ v2f fma2(v2f a, v2f b, v2f c) {
  return __builtin_elementwise_fma(a, b, c);
}
__device__ __forceinline__ v2f max2(v2f a, v2f b) {
  return __builtin_elementwise_max(a, b);
}

// ---------------------------------------------------------------------------
// init: packed point records (x,y,z, 0.5*|p|^2), zero potentials, zero output,
// static colpack position parts (both buffers).
// ---------------------------------------------------------------------------
__global__ __launch_bounds__(256) void emd_init(const float* __restrict__ x,
                                                const float* __restrict__ y,
                                                float4* __restrict__ x4,
                                                float4* __restrict__ y4,
                                                float* __restrict__ pot0,
                                                float* __restrict__ cpk0,
                                                float* __restrict__ cpk1,
                                                float* __restrict__ out) {
  int t = blockIdx.x * blockDim.x + threadIdx.x;  // 0..65535
  if (t < NB * NPTS) {
    float a0 = x[3 * t], a1 = x[3 * t + 1], a2 = x[3 * t + 2];
    x4[t] = make_float4(a0, a1, a2, 0.5f * (a0 * a0 + a1 * a1 + a2 * a2));
    float b0 = y[3 * t], b1 = y[3 * t + 1], b2 = y[3 * t + 2];
    y4[t] = make_float4(b0, b1, b2, 0.5f * (b0 * b0 + b1 * b1 + b2 * b2));
  }
  pot0[t] = 0.0f;
  {
    // one colpack column entry per thread: t -> (mat, b, col)
    int mat = t >> 14;
    int b = (t >> 11) & 7;
    int col = t & 2047;
    // cols: mat0 -> y, mat1 -> x, mat2 -> x, mat3 -> y
    const float* src = (mat == 1 || mat == 2) ? x : y;
    int si = (b * NPTS + col) * 3;
    float qx = src[si], qy = src[si + 1], qz = src[si + 2];
    int p = col >> 1, par = col & 1;
    int g = p >> 2, sl = p & 3;
    int base = (mat * NB + b) * CPK_FLOATS + g * 32;
    cpk0[base + sl * 4 + par] = qx;
    cpk0[base + sl * 4 + 2 + par] = qy;
    cpk0[base + 16 + sl * 4 + par] = qz;
    cpk1[base + sl * 4 + par] = qx;
    cpk1[base + sl * 4 + 2 + par] = qy;
    cpk1[base + 16 + sl * 4 + par] = qz;
    // h-slot (base+16+sl*4+2+par) is written by the producing sweep's merge.
  }
  if (t == 0) out[0] = 0.0f;
}

// ---------------------------------------------------------------------------
// Shared geometry: 512 blocks x 1024 threads; block=(mat,b,128-row group);
// 16 waves = column chunks of 128 cols (64 pairs); R=2 rows/thread.
// ---------------------------------------------------------------------------

// Bootstrap sweep: exact online softmax (first eps only) + amax store.
// Keeps the original LDS-staging path (runs once); merge additionally packs
// next sweep's colpack h-parts.
__global__ __launch_bounds__(1024, 8) void emd_sweep_boot(
    const float4* __restrict__ x4, const float4* __restrict__ y4,
    const float* __restrict__ pot_in, float* __restrict__ pot_out,
    float* __restrict__ amax_out, float* __restrict__ cpk_out, float c,
    float neg_eps_ln2, float eps_logM, float cnext) {
  __shared__ union {
    struct {
      float4 A[NPTS / 2];
      float4 B[NPTS / 2];
    } cp;
    struct {
      float m[NW][BROWS];
      float l[NW][BROWS];
    } mg;
  } sh;

  int blk = blockIdx.x;            // 0..511
  int mat = blk >> 7;
  int b = (blk >> 4) & 7;
  int rg = blk & 15;               // 128-row group
  int tid = threadIdx.x;
  int lane = tid & 63;
  int w = tid >> 6;                // 0..15

  const float4* rowp = (mat == 1 || mat == 3) ? y4 : x4;
  const float4* colp = (mat == 0 || mat == 3) ? y4 : x4;
  int hidx = (mat < 2) ? (mat ^ 1) : mat;
  const float* h = pot_in + (hidx * NB + b) * NPTS;
  const float4* colb = colp + b * NPTS;

  {
    float4 q0 = colb[2 * tid];
    float4 q1 = colb[2 * tid + 1];
    float2 hv = ((const float2*)h)[tid];
    sh.cp.A[tid] = make_float4(q0.x, q1.x, q0.y, q1.y);
    sh.cp.B[tid] = make_float4(q0.z, q1.z, (hv.x - q0.w) * c, (hv.y - q1.w) * c);
  }
  __syncthreads();

  int rowbase = rg * BROWS;
  const float4* rowb = rowp + b * NPTS + rowbase;

  v2f xs0[R], xs1[R], xs2[R];
  float m[R], l[R];
#pragma unroll
  for (int r = 0; r < R; ++r) {
    float4 p = rowb[r * 64 + lane];
    float a0 = p.x * c, a1 = p.y * c, a2 = p.z * c;
    xs0[r] = (v2f){a0, a0};
    xs1[r] = (v2f){a1, a1};
    xs2[r] = (v2f){a2, a2};
    m[r] = -INFINITY;
    l[r] = 0.0f;
  }

  int p0 = w * CPAIR;
  for (int tp = 0; tp < CPAIR; tp += 4) {
    float4 A[4], B[4];
#pragma unroll
    for (int j = 0; j < 4; ++j) {
      A[j] = sh.cp.A[p0 + tp + j];
      B[j] = sh.cp.B[p0 + tp + j];
    }
#pragma unroll
    for (int r = 0; r < R; ++r) {
      v2f s2[4];
#pragma unroll
      for (int j = 0; j < 4; ++j) {
        v2f qx = {A[j].x, A[j].y};
        v2f qy = {A[j].z, A[j].w};
        v2f qz = {B[j].x, B[j].y};
        v2f qw = {B[j].z, B[j].w};
        s2[j] = fma2(xs0[r], qx, fma2(xs1[r], qy, fma2(xs2[r], qz, qw)));
      }
      v2f t0 = max2(s2[0], s2[1]);
      v2f t1 = max2(s2[2], s2[3]);
      v2f u = max2(t0, t1);
      float mt = fmaxf(u.x, u.y);
      float mn = fmaxf(m[r], mt);
      v2f mn2 = {mn, mn};
      v2f acc = {0.0f, 0.0f};
#pragma unroll
      for (int j = 0; j < 4; ++j) {
        v2f d = s2[j] - mn2;
        v2f e;
        e.x = wexp2(d.x);
        e.y = wexp2(d.y);
        acc += e;
      }
      float er = wexp2(m[r] - mn);
      l[r] = fmaf(l[r], er, acc.x + acc.y);
      m[r] = mn;
    }
  }

  __syncthreads();
#pragma unroll
  for (int r = 0; r < R; ++r) {
    sh.mg.m[w][r * 64 + lane] = m[r];
    sh.mg.l[w][r * 64 + lane] = l[r];
  }
  __syncthreads();

  if (w < 2) {
    int row = w * 64 + lane;       // 0..127
    float M = sh.mg.m[0][row];
#pragma unroll
    for (int q = 1; q < NW; ++q) M = fmaxf(M, sh.mg.m[q][row]);
    float L = 0.0f;
#pragma unroll
    for (int q = 0; q < NW; ++q)
      L += sh.mg.l[q][row] * wexp2(sh.mg.m[q][row] - M);
    float pw = rowb[row].w;
    float res = pw + neg_eps_ln2 * (M + log2f(L)) + eps_logM;
    float invc = -neg_eps_ln2;     // = 1/c
    amax_out[(mat * NB + b) * NPTS + rowbase + row] = M * invc;
    const float* oldp = pot_in + (mat * NB + b) * NPTS + rowbase;
    float* outp = pot_out + (mat * NB + b) * NPTS + rowbase;
    float np = 0.5f * (oldp[row] + res);
    outp[row] = np;
    // pack next sweep's colpack h-part: potential of mat feeds columns of mp
    int mp = (mat < 2) ? (mat ^ 1) : mat;
    int col = rowbase + row;
    int p = col >> 1, par = col & 1, g = p >> 2, sl = p & 3;
    cpk_out[(mp * NB + b) * CPK_FLOATS + g * 32 + 16 + sl * 4 + 2 + par] =
        (np - pw) * cnext;
  }
}

// Fixed-reference sweep: exp2(s - Mref), Mref = amax_in[row]*c. Exact LSE;
// amax_out = (Mref + log2 L)/c self-corrects. Column records streamed through
// the SCALAR path (s_load -> SGPRs) instead of LDS broadcast: removes the
// LDS-return bottleneck (8 x ds_read_b128 per wave-iter).
template <bool FINAL>
__global__ __launch_bounds__(1024, 8) void emd_sweep_ref(
    const float4* __restrict__ x4, const float4* __restrict__ y4,
    const float* __restrict__ pot_in, float* __restrict__ pot_out,
    const float* __restrict__ amax_in, float* __restrict__ amax_out,
    const float* __restrict__ cpk_in, float* __restrict__ cpk_out,
    float* __restrict__ out, float c, float neg_eps_ln2, float eps_logM,
    float cnext) {
  __shared__ float lbuf[NW][BROWS];  // 8 KB merge buffer

  int blk = blockIdx.x;            // 0..511
  int mat = blk >> 7;
  int b = (blk >> 4) & 7;
  int rg = blk & 15;
  int tid = threadIdx.x;
  int lane = tid & 63;
  int w = tid >> 6;

  const float4* rowp = (mat == 1 || mat == 3) ? y4 : x4;

  int rowbase = rg * BROWS;
  const float4* rowb = rowp + b * NPTS + rowbase;
  const float* amrow = amax_in + (mat * NB + b) * NPTS + rowbase;

  v2f xs0[R], xs1[R], xs2[R], mref2[R], acc[R];
#pragma unroll
  for (int r = 0; r < R; ++r) {
    float4 p = rowb[r * 64 + lane];
    float a0 = p.x * c, a1 = p.y * c, a2 = p.z * c;
    xs0[r] = (v2f){a0, a0};
    xs1[r] = (v2f){a1, a1};
    xs2[r] = (v2f){a2, a2};
    float mr = amrow[r * 64 + lane] * c;
    mref2[r] = (v2f){mr, mr};
    acc[r] = (v2f){0.0f, 0.0f};
  }

  // wave-uniform base: wave w owns pairs [w*64, w*64+63] = groups [w*16, w*16+15]
  int wu = __builtin_amdgcn_readfirstlane(w);
  unsigned long long cp0 =
      (unsigned long long)(cpk_in + (mat * NB + b) * CPK_FLOATS) +
      (unsigned long long)(wu * 2048);  // 16 groups * 128B

  for (int it = 0; it < 16; ++it) {    // 1 group = 4 pairs = 8 cols per iter
    unsigned long long addr = cp0 + (unsigned)(it * 128);
    v8f a0, a1, b0, b1;
    asm volatile(
        "s_load_dwordx8 %0, %4, 0x0\n\t"
        "s_load_dwordx8 %1, %4, 0x20\n\t"
        "s_load_dwordx8 %2, %4, 0x40\n\t"
        "s_load_dwordx8 %3, %4, 0x60\n\t"
        "s_waitcnt lgkmcnt(0)"
        : "=s"(a0), "=s"(a1), "=s"(b0), "=s"(b1)
        : "s"(addr));
#pragma unroll
    for (int j = 0; j < 4; ++j) {
      v8f va = (j < 2) ? a0 : a1;
      v8f vb = (j < 2) ? b0 : b1;
      int o = (j & 1) * 4;
      v2f qx = {va[o], va[o + 1]};
      v2f qy = {va[o + 2], va[o + 3]};
      v2f qz = {vb[o], vb[o + 1]};
      v2f qw = {vb[o + 2], vb[o + 3]};
#pragma unroll
      for (int r = 0; r < R; ++r) {
        v2f s2 = fma2(xs0[r], qx, fma2(xs1[r], qy, fma2(xs2[r], qz, qw)));
        v2f d = s2 - mref2[r];
        v2f e;
        e.x = wexp2(d.x);
        e.y = wexp2(d.y);
        acc[r] += e;
      }
    }
  }

#pragma unroll
  for (int r = 0; r < R; ++r)
    lbuf[w][r * 64 + lane] = acc[r].x + acc[r].y;
  __syncthreads();

  if (w < 2) {
    int row = w * 64 + lane;       // 0..127
    float L = lbuf[0][row];
#pragma unroll
    for (int q = 1; q < NW; ++q) L += lbuf[q][row];
    float mr = amrow[row] * c;
    float lse = mr + log2f(L);
    float pw = rowb[row].w;
    float res = pw + neg_eps_ln2 * lse + eps_logM;
    float invc = -neg_eps_ln2;
    if (FINAL) {
      float sign = (mat < 2) ? 1.0f : -1.0f;
      float val = sign * res * (1.0f / (float)(NB * NPTS));
#pragma unroll
      for (int off = 32; off; off >>= 1) val += __shfl_xor(val, off);
      if (lane == 0) atomicAdd(out, val);
    } else {
      amax_out[(mat * NB + b) * NPTS + rowbase + row] = lse * invc;
      const float* oldp = pot_in + (mat * NB + b) * NPTS + rowbase;
      float* outp = pot_out + (mat * NB + b) * NPTS + rowbase;
      float np = 0.5f * (oldp[row] + res);
      outp[row] = np;
      int mp = (mat < 2) ? (mat ^ 1) : mat;
      int col = rowbase + row;
      int p = col >> 1, par = col & 1, g = p >> 2, sl = p & 3;
      cpk_out[(mp * NB + b) * CPK_FLOATS + g * 32 + 16 + sl * 4 + 2 + par] =
          (np - pw) * cnext;
    }
  }
}

// ---------------------------------------------------------------------------
extern "C" void kernel_launch(void* const* d_in, const int* in_sizes, int n_in,
                              void* d_out, int out_size, void* d_ws, size_t ws_size,
                              hipStream_t stream) {
  const float* x = (const float*)d_in[0];
  const float* y = (const float*)d_in[1];
  float* out = (float*)d_out;

  char* ws = (char*)d_ws;
  float4* x4 = (float4*)ws;                        // 256 KB
  float4* y4 = (float4*)(ws + 262144);             // 256 KB
  float* pot = (float*)(ws + 524288);              // 2 * 65536 floats = 512 KB
  float* amax = (float*)(ws + 1048576);            // 65536 floats = 256 KB
  float* cpk[2] = {(float*)(ws + 1310720),         // 1 MB
                   (float*)(ws + 2359296)};        // 1 MB

  emd_init<<<256, 256, 0, stream>>>(x, y, x4, y4, pot, cpk[0], cpk[1], out);

  // eps schedule: s=8.0, *=0.9 while s>0.01; eps = f32(s)^2; append 0.01^2
  float eps_arr[80];
  int ne = 0;
  double s = 8.0;
  while (s > 0.01) {
    float sf = (float)s;
    eps_arr[ne++] = sf * sf;
    s *= 0.9;
  }
  {
    float bf = 0.01f;
    eps_arr[ne++] = bf * bf;
  }

  const double LOG2E = 1.4426950408889634;
  const double LN2 = 0.6931471805599453;
  const double LOG2048 = 7.624618986159398;

  float c_arr[80];
  for (int k = 0; k < ne; ++k) c_arr[k] = (float)(LOG2E / (double)eps_arr[k]);

  int cur = 0;
  for (int k = 0; k < ne; ++k) {
    float eps = eps_arr[k];
    float ck = c_arr[k];
    float nel = (float)(-(double)eps * LN2);
    float elM = (float)((double)eps * LOG2048);
    float cn = (k + 1 < ne) ? c_arr[k + 1] : c_arr[ne - 1];
    if (k == 0) {
      emd_sweep_boot<<<512, 1024, 0, stream>>>(
          x4, y4, pot + cur * 65536, pot + (1 - cur) * 65536, amax,
          cpk[1 - cur], ck, nel, elM, cn);
    } else {
      emd_sweep_ref<false><<<512, 1024, 0, stream>>>(
          x4, y4, pot + cur * 65536, pot + (1 - cur) * 65536, amax, amax,
          cpk[cur], cpk[1 - cur], out, ck, nel, elM, cn);
    }
    cur ^= 1;
  }

  {
    float eps = eps_arr[ne - 1];
    float ck = c_arr[ne - 1];
    float nel = (float)(-(double)eps * LN2);
    float elM = (float)((double)eps * LOG2048);
    emd_sweep_ref<true><<<512, 1024, 0, stream>>>(
        x4, y4, pot + cur * 65536, nullptr, amax, nullptr, cpk[cur], nullptr,
        out, ck, nel, elM, 0.0f);
  }
}

// Round 2
// 1442.219 us; speedup vs baseline: 1.0617x; 1.0617x over previous
//
#include <hip/hip_runtime.h>
#include <math.h>

#define NPTS 2048
#define NB 8
#define R 4        // rows per thread
#define NW 16      // waves per block = column chunks
#define BROWS 256  // rows per block (64 lanes * R)
#define CPAIR 64   // col-pairs per wave chunk (128 cols)

typedef float v2f __attribute__((ext_vector_type(2)));

__device__ __forceinline__ float wexp2(float v) { return __builtin_amdgcn_exp2f(v); }
__device__ __forceinline__ v2f fma2(v2f a, v2f b, v2f c) {
  return __builtin_elementwise_fma(a, b, c);
}
__device__ __forceinline__ v2f max2(v2f a, v2f b) {
  return __builtin_elementwise_max(a, b);
}

// ---------------------------------------------------------------------------
// init: packed point records (x,y,z, 0.5*|p|^2), zero potentials, zero output.
// ---------------------------------------------------------------------------
__global__ __launch_bounds__(256) void emd_init(const float* __restrict__ x,
                                                const float* __restrict__ y,
                                                float4* __restrict__ x4,
                                                float4* __restrict__ y4,
                                                float* __restrict__ pot0,
                                                float* __restrict__ out) {
  int t = blockIdx.x * blockDim.x + threadIdx.x;  // 0..65535
  if (t < NB * NPTS) {
    float a0 = x[3 * t], a1 = x[3 * t + 1], a2 = x[3 * t + 2];
    x4[t] = make_float4(a0, a1, a2, 0.5f * (a0 * a0 + a1 * a1 + a2 * a2));
    float b0 = y[3 * t], b1 = y[3 * t + 1], b2 = y[3 * t + 2];
    y4[t] = make_float4(b0, b1, b2, 0.5f * (b0 * b0 + b1 * b1 + b2 * b2));
  }
  pot0[t] = 0.0f;
  if (t == 0) out[0] = 0.0f;
}

// ---------------------------------------------------------------------------
// Shared geometry: 256 blocks x 1024 threads; block=(mat,b,256-row group);
// 16 waves = column chunks of 128 cols (64 pairs); R=4 rows/thread.
// 1 block/CU (4 waves/SIMD). LDS broadcast reads amortized over 4 rows:
// 8 B/elem -> 4 B/elem, the binding LDS-return pipe halves.
// Column pair packed A=(x0,x1,y0,y1), B=(z0,z1,w0,w1), w=(h-0.5|q|^2)*c.
// ---------------------------------------------------------------------------

// Bootstrap sweep: exact online softmax (first eps only) + amax store.
__global__ __launch_bounds__(1024, 4) void emd_sweep_boot(
    const float4* __restrict__ x4, const float4* __restrict__ y4,
    const float* __restrict__ pot_in, float* __restrict__ pot_out,
    float* __restrict__ amax_out, float c, float neg_eps_ln2, float eps_logM) {
  __shared__ union {
    struct {
      float4 A[NPTS / 2];          // 16 KB
      float4 B[NPTS / 2];          // 16 KB
    } cp;
    struct {
      float m[NW][BROWS];          // 16 KB
      float l[NW][BROWS];          // 16 KB
    } mg;
  } sh;

  int blk = blockIdx.x;            // 0..255
  int mat = blk >> 6;
  int b = (blk >> 3) & 7;
  int rg = blk & 7;                // 256-row group
  int tid = threadIdx.x;
  int lane = tid & 63;
  int w = tid >> 6;                // 0..15

  const float4* rowp = (mat == 1 || mat == 3) ? y4 : x4;
  const float4* colp = (mat == 0 || mat == 3) ? y4 : x4;
  int hidx = (mat < 2) ? (mat ^ 1) : mat;
  const float* h = pot_in + (hidx * NB + b) * NPTS;
  const float4* colb = colp + b * NPTS;

  {
    float4 q0 = colb[2 * tid];
    float4 q1 = colb[2 * tid + 1];
    float2 hv = ((const float2*)h)[tid];
    sh.cp.A[tid] = make_float4(q0.x, q1.x, q0.y, q1.y);
    sh.cp.B[tid] = make_float4(q0.z, q1.z, (hv.x - q0.w) * c, (hv.y - q1.w) * c);
  }
  __syncthreads();

  int rowbase = rg * BROWS;
  const float4* rowb = rowp + b * NPTS + rowbase;

  v2f xs0[R], xs1[R], xs2[R];
  float m[R], l[R];
#pragma unroll
  for (int r = 0; r < R; ++r) {
    float4 p = rowb[r * 64 + lane];
    float a0 = p.x * c, a1 = p.y * c, a2 = p.z * c;
    xs0[r] = (v2f){a0, a0};
    xs1[r] = (v2f){a1, a1};
    xs2[r] = (v2f){a2, a2};
    m[r] = -INFINITY;
    l[r] = 0.0f;
  }

  int p0 = w * CPAIR;
  for (int tp = 0; tp < CPAIR; tp += 4) {
    float4 A[4], B[4];
#pragma unroll
    for (int j = 0; j < 4; ++j) {
      A[j] = sh.cp.A[p0 + tp + j];
      B[j] = sh.cp.B[p0 + tp + j];
    }
#pragma unroll
    for (int r = 0; r < R; ++r) {
      v2f s2[4];
#pragma unroll
      for (int j = 0; j < 4; ++j) {
        v2f qx = {A[j].x, A[j].y};
        v2f qy = {A[j].z, A[j].w};
        v2f qz = {B[j].x, B[j].y};
        v2f qw = {B[j].z, B[j].w};
        s2[j] = fma2(xs0[r], qx, fma2(xs1[r], qy, fma2(xs2[r], qz, qw)));
      }
      v2f t0 = max2(s2[0], s2[1]);
      v2f t1 = max2(s2[2], s2[3]);
      v2f u = max2(t0, t1);
      float mt = fmaxf(u.x, u.y);
      float mn = fmaxf(m[r], mt);
      v2f mn2 = {mn, mn};
      v2f acc = {0.0f, 0.0f};
#pragma unroll
      for (int j = 0; j < 4; ++j) {
        v2f d = s2[j] - mn2;
        v2f e;
        e.x = wexp2(d.x);
        e.y = wexp2(d.y);
        acc += e;
      }
      float er = wexp2(m[r] - mn);
      l[r] = fmaf(l[r], er, acc.x + acc.y);
      m[r] = mn;
    }
  }

  __syncthreads();
#pragma unroll
  for (int r = 0; r < R; ++r) {
    sh.mg.m[w][r * 64 + lane] = m[r];
    sh.mg.l[w][r * 64 + lane] = l[r];
  }
  __syncthreads();

  if (w < 4) {
    int row = w * 64 + lane;       // 0..255
    float M = sh.mg.m[0][row];
#pragma unroll
    for (int q = 1; q < NW; ++q) M = fmaxf(M, sh.mg.m[q][row]);
    float L = 0.0f;
#pragma unroll
    for (int q = 0; q < NW; ++q)
      L += sh.mg.l[q][row] * wexp2(sh.mg.m[q][row] - M);
    float pw = rowb[row].w;
    float res = pw + neg_eps_ln2 * (M + log2f(L)) + eps_logM;
    float invc = -neg_eps_ln2;     // = 1/c
    amax_out[(mat * NB + b) * NPTS + rowbase + row] = M * invc;
    const float* oldp = pot_in + (mat * NB + b) * NPTS + rowbase;
    float* outp = pot_out + (mat * NB + b) * NPTS + rowbase;
    outp[row] = 0.5f * (oldp[row] + res);
  }
}

// Fixed-reference sweep: exp2(s - Mref), Mref = amax_in[row]*c. Exact LSE;
// amax_out = (Mref + log2 L)/c self-corrects (always within +11 of true max).
template <bool FINAL>
__global__ __launch_bounds__(1024, 4) void emd_sweep_ref(
    const float4* __restrict__ x4, const float4* __restrict__ y4,
    const float* __restrict__ pot_in, float* __restrict__ pot_out,
    const float* __restrict__ amax_in, float* __restrict__ amax_out,
    float* __restrict__ out, float c, float neg_eps_ln2, float eps_logM) {
  __shared__ union {
    struct {
      float4 A[NPTS / 2];          // 16 KB
      float4 B[NPTS / 2];          // 16 KB
    } cp;
    float lbuf[NW][BROWS];         // merge phase (colpack dead), 16 KB
  } sh;

  int blk = blockIdx.x;            // 0..255
  int mat = blk >> 6;
  int b = (blk >> 3) & 7;
  int rg = blk & 7;
  int tid = threadIdx.x;
  int lane = tid & 63;
  int w = tid >> 6;

  const float4* rowp = (mat == 1 || mat == 3) ? y4 : x4;
  const float4* colp = (mat == 0 || mat == 3) ? y4 : x4;
  int hidx = (mat < 2) ? (mat ^ 1) : mat;
  const float* h = pot_in + (hidx * NB + b) * NPTS;
  const float4* colb = colp + b * NPTS;

  {
    float4 q0 = colb[2 * tid];
    float4 q1 = colb[2 * tid + 1];
    float2 hv = ((const float2*)h)[tid];
    sh.cp.A[tid] = make_float4(q0.x, q1.x, q0.y, q1.y);
    sh.cp.B[tid] = make_float4(q0.z, q1.z, (hv.x - q0.w) * c, (hv.y - q1.w) * c);
  }

  int rowbase = rg * BROWS;
  const float4* rowb = rowp + b * NPTS + rowbase;
  const float* amrow = amax_in + (mat * NB + b) * NPTS + rowbase;

  v2f xs0[R], xs1[R], xs2[R], mref2[R], acc[R];
#pragma unroll
  for (int r = 0; r < R; ++r) {
    float4 p = rowb[r * 64 + lane];
    float a0 = p.x * c, a1 = p.y * c, a2 = p.z * c;
    xs0[r] = (v2f){a0, a0};
    xs1[r] = (v2f){a1, a1};
    xs2[r] = (v2f){a2, a2};
    float mr = amrow[r * 64 + lane] * c;
    mref2[r] = (v2f){mr, mr};
    acc[r] = (v2f){0.0f, 0.0f};
  }
  __syncthreads();

  int p0 = w * CPAIR;
  for (int tp = 0; tp < CPAIR; tp += 4) {   // 4 pairs = 8 cols per iter
    float4 A[4], B[4];
#pragma unroll
    for (int j = 0; j < 4; ++j) {
      A[j] = sh.cp.A[p0 + tp + j];
      B[j] = sh.cp.B[p0 + tp + j];
    }
#pragma unroll
    for (int r = 0; r < R; ++r) {
#pragma unroll
      for (int j = 0; j < 4; ++j) {
        v2f qx = {A[j].x, A[j].y};
        v2f qy = {A[j].z, A[j].w};
        v2f qz = {B[j].x, B[j].y};
        v2f qw = {B[j].z, B[j].w};
        v2f s2 = fma2(xs0[r], qx, fma2(xs1[r], qy, fma2(xs2[r], qz, qw)));
        v2f d = s2 - mref2[r];
        v2f e;
        e.x = wexp2(d.x);
        e.y = wexp2(d.y);
        acc[r] += e;
      }
    }
  }

  __syncthreads();  // colpack dead; safe to overwrite (union)
#pragma unroll
  for (int r = 0; r < R; ++r)
    sh.lbuf[w][r * 64 + lane] = acc[r].x + acc[r].y;
  __syncthreads();

  if (w < 4) {
    int row = w * 64 + lane;       // 0..255
    float L = sh.lbuf[0][row];
#pragma unroll
    for (int q = 1; q < NW; ++q) L += sh.lbuf[q][row];
    float mr = amrow[row] * c;
    float lse = mr + log2f(L);
    float pw = rowb[row].w;
    float res = pw + neg_eps_ln2 * lse + eps_logM;
    float invc = -neg_eps_ln2;
    if (FINAL) {
      float sign = (mat < 2) ? 1.0f : -1.0f;
      float val = sign * res * (1.0f / (float)(NB * NPTS));
#pragma unroll
      for (int off = 32; off; off >>= 1) val += __shfl_xor(val, off);
      if (lane == 0) atomicAdd(out, val);
    } else {
      amax_out[(mat * NB + b) * NPTS + rowbase + row] = lse * invc;
      const float* oldp = pot_in + (mat * NB + b) * NPTS + rowbase;
      float* outp = pot_out + (mat * NB + b) * NPTS + rowbase;
      outp[row] = 0.5f * (oldp[row] + res);
    }
  }
}

// ---------------------------------------------------------------------------
extern "C" void kernel_launch(void* const* d_in, const int* in_sizes, int n_in,
                              void* d_out, int out_size, void* d_ws, size_t ws_size,
                              hipStream_t stream) {
  const float* x = (const float*)d_in[0];
  const float* y = (const float*)d_in[1];
  float* out = (float*)d_out;

  char* ws = (char*)d_ws;
  float4* x4 = (float4*)ws;                        // 256 KB
  float4* y4 = (float4*)(ws + 262144);             // 256 KB
  float* pot = (float*)(ws + 524288);              // 2 * 65536 floats = 512 KB
  float* amax = (float*)(ws + 1048576);            // 65536 floats = 256 KB

  emd_init<<<256, 256, 0, stream>>>(x, y, x4, y4, pot, out);

  // eps schedule: s=8.0, *=0.9 while s>0.01; eps = f32(s)^2; append 0.01^2
  float eps_arr[80];
  int ne = 0;
  double s = 8.0;
  while (s > 0.01) {
    float sf = (float)s;
    eps_arr[ne++] = sf * sf;
    s *= 0.9;
  }
  {
    float bf = 0.01f;
    eps_arr[ne++] = bf * bf;
  }

  const double LOG2E = 1.4426950408889634;
  const double LN2 = 0.6931471805599453;
  const double LOG2048 = 7.624618986159398;

  int cur = 0;
  for (int k = 0; k < ne; ++k) {
    float eps = eps_arr[k];
    float c = (float)(LOG2E / (double)eps);
    float nel = (float)(-(double)eps * LN2);
    float elM = (float)((double)eps * LOG2048);
    if (k == 0) {
      emd_sweep_boot<<<256, 1024, 0, stream>>>(x4, y4, pot + cur * 65536,
                                               pot + (1 - cur) * 65536, amax,
                                               c, nel, elM);
    } else {
      emd_sweep_ref<false><<<256, 1024, 0, stream>>>(
          x4, y4, pot + cur * 65536, pot + (1 - cur) * 65536, amax, amax, out,
          c, nel, elM);
    }
    cur ^= 1;
  }

  {
    float eps = eps_arr[ne - 1];
    float c = (float)(LOG2E / (double)eps);
    float nel = (float)(-(double)eps * LN2);
    float elM = (float)((double)eps * LOG2048);
    emd_sweep_ref<true><<<256, 1024, 0, stream>>>(
        x4, y4, pot + cur * 65536, nullptr, amax, nullptr, out, c, nel, elM);
  }
}